// Round 4
// baseline (229.129 us; speedup 1.0000x reference)
//
#include <hip/hip_runtime.h>

// Walsh-Hadamard transform, N=4096/row, fp32, scale 1/64.
// H4096 = H16^3 over hex digits a(0-3), b(4-7), c(8-11); e = c*256+b*16+a.
// Persistent blocks (1024 = 4/CU), 8 rows each, software-pipelined:
// next row's global loads are issued BEFORE the barriers and ride across
// them via a custom lgkmcnt-only barrier (avoids the vmcnt(0) drain that
// __syncthreads() forces -- the round-3 stall). Two LDS buffers -> 2
// barriers/row. Contiguous dwordx4 loads; strided dword stores.

constexpr int N = 4096;
constexpr int S = 17;                 // LDS row stride 16+1 (round-0-verified patterns)
constexpr int NBLOCKS = 1024;         // 4 blocks/CU * 256 CUs
constexpr int ROWS_PER_BLOCK = 8192 / NBLOCKS;

// Barrier that drains LDS ops only; outstanding global loads stay in flight.
#define BAR_LGKM() asm volatile("s_waitcnt lgkmcnt(0)\ns_barrier" ::: "memory")

__device__ __forceinline__ void wht16(float v[16]) {
#pragma unroll
    for (int m = 1; m < 16; m <<= 1) {
#pragma unroll
        for (int g = 0; g < 16; g += 2 * m) {
#pragma unroll
            for (int k = 0; k < m; ++k) {
                float a = v[g + k];
                float b = v[g + k + m];
                v[g + k]     = a + b;
                v[g + k + m] = a - b;
            }
        }
    }
}

__device__ __forceinline__ void load16(float v[16], const float* __restrict__ p) {
    const float4* s4 = (const float4*)p;
    float4 f0 = s4[0], f1 = s4[1], f2 = s4[2], f3 = s4[3];
    v[0]=f0.x;  v[1]=f0.y;  v[2]=f0.z;  v[3]=f0.w;
    v[4]=f1.x;  v[5]=f1.y;  v[6]=f1.z;  v[7]=f1.w;
    v[8]=f2.x;  v[9]=f2.y;  v[10]=f2.z; v[11]=f2.w;
    v[12]=f3.x; v[13]=f3.y; v[14]=f3.z; v[15]=f3.w;
}

// T1: logical i = c*256 + a*16 + b, phys(i) = (i>>4)*S + (i&15)
__device__ __forceinline__ void t1_write(float* lds, const float v[16], int t) {
    const int base = (t >> 4) * (16 * S) + (t & 15);
#pragma unroll
    for (int j = 0; j < 16; ++j) lds[base + j * S] = v[j];
}
// T2: logical i2 = b*256 + a*16 + c (thread owns c=t>>4, a=t&15; p indexes b)
__device__ __forceinline__ void t2_write(float* lds, const float v[16], int t) {
    const int base = (t & 15) * S + (t >> 4);
#pragma unroll
    for (int p = 0; p < 16; ++p) lds[base + p * (16 * S)] = v[p];
}
__device__ __forceinline__ void rd16(const float* lds, float v[16], int t) {
    const int base = t * S;
#pragma unroll
    for (int p = 0; p < 16; ++p) v[p] = lds[base + p];
}

// LDS 2*17408 = 34816 B -> 4 blocks/CU (16 waves); VGPR ~64 fits bounds(256,4).
__global__ __launch_bounds__(256, 4) void fwht4096_kernel(const float* __restrict__ in,
                                                          float* __restrict__ out) {
    __shared__ float ldsA[256 * S];
    __shared__ float ldsB[256 * S];

    const int t = threadIdx.x;
    size_t row = blockIdx.x;
    const float scale = 0.015625f;    // 1/sqrt(4096)

    float v[16], pf[16];
    load16(v, in + row * (size_t)N + t * 16);

#pragma unroll 1
    for (int it = 0; it < ROWS_PER_BLOCK; ++it) {
        const size_t nrow = row + NBLOCKS;
        const bool has_next = (it + 1 < ROWS_PER_BLOCK);

        wht16(v);                              // digit a
        t1_write(ldsA, v, t);
        if (has_next) load16(pf, in + nrow * (size_t)N + t * 16);  // prefetch: rides across barriers
        BAR_LGKM();

        rd16(ldsA, v, t);                      // owns (c=t>>4, a=t&15), p=b
        wht16(v);                              // digit b
        t2_write(ldsB, v, t);
        BAR_LGKM();

        rd16(ldsB, v, t);                      // owns (b=t>>4, a=t&15), p=c
        wht16(v);                              // digit c

        float* __restrict__ dst = out + row * (size_t)N;
#pragma unroll
        for (int p = 0; p < 16; ++p) dst[p * 256 + t] = v[p] * scale;  // fire-and-forget

        if (has_next) {
#pragma unroll
            for (int q = 0; q < 16; ++q) v[q] = pf[q];
            row = nrow;
        }
    }
}

extern "C" void kernel_launch(void* const* d_in, const int* in_sizes, int n_in,
                              void* d_out, int out_size, void* d_ws, size_t ws_size,
                              hipStream_t stream) {
    const float* x = (const float*)d_in[0];
    float* y = (float*)d_out;
    fwht4096_kernel<<<NBLOCKS, 256, 0, stream>>>(x, y);
}